// Round 4
// baseline (234.337 us; speedup 1.0000x reference)
//
#include <hip/hip_runtime.h>

constexpr int BATCH = 1048576;
constexpr int H = 20;        // hidden
constexpr int BLK = 256;     // threads per block
constexpr int RPT = 2;       // batch rows per thread (packed fp32)
constexpr int ROWS = BLK * RPT;   // 512 rows per block
constexpr int RS = 21;       // padded LDS row stride (gcd(21,32)=1)
constexpr int TILEF = ROWS * H;   // 10240 floats per tile

typedef float v2f __attribute__((ext_vector_type(2)));

__device__ __forceinline__ v2f splat2(float s) { v2f r; r.x = s; r.y = s; return r; }

// Branch-free, per-lane BIT-IDENTICAL to the validated if/else version:
//  z>=0: e=expf(-z), 1/(1+e)   |   z<0: e=expf(z), e/(1+e)
__device__ __forceinline__ float sigmoidf_stable(float z) {
    const float e = expf(-fabsf(z));
    const float n = (z >= 0.0f) ? 1.0f : e;
    return n / (1.0f + e);
}

// Identical op order to the validated R1-R3 kernels.
__device__ __forceinline__ void sample_row(float l0, float l1, float l2, float uv,
                                           float& act_out, float& slp_out) {
    const float m = fmaxf(fmaxf(l0, l1), l2);
    const float s = expf(l0 - m) + expf(l1 - m) + expf(l2 - m);
    const float lse = m + logf(s);
    const float lp0 = l0 - lse, lp1 = l1 - lse, lp2 = l2 - lse;
    const float p0 = expf(lp0), p1 = expf(lp1), p2 = expf(lp2);
    const float c0 = p0;
    const float c1 = c0 + p1;
    const float c2 = c1 + p2;
    int act = (int)(c0 < uv) + (int)(c1 < uv) + (int)(c2 < uv);
    act = act > 2 ? 2 : act;
    slp_out = (act == 0) ? lp0 : ((act == 1) ? lp1 : lp2);
    act_out = (float)act;
}

__global__ __launch_bounds__(BLK) void lstm_coord_kernel(
    const float* __restrict__ x,
    const float* __restrict__ hx,
    const float* __restrict__ cx,
    const float* __restrict__ u,
    const float* __restrict__ W_ih,
    const float* __restrict__ W_hh,
    const float* __restrict__ b_ih,
    const float* __restrict__ b_hh,
    const float* __restrict__ W_dec,
    const float* __restrict__ b_dec,
    float* __restrict__ out)
{
    // One shared tile buffer, reused for hx -> cx -> h -> c (43008 B).
    __shared__ float sT[ROWS * RS];

    const int t = threadIdx.x;
    const size_t base = (size_t)blockIdx.x * TILEF;   // float offset of block tile
    const int gtid = blockIdx.x * BLK + t;            // thread id over B/2 pairs

    // ---- stage hx tile (coalesced float4 -> padded LDS) ----
#pragma unroll
    for (int j = 0; j < 10; ++j) {
        const int g = 4 * (t + BLK * j);              // 0..10236
        float4 v = *reinterpret_cast<const float4*>(hx + base + g);
#pragma unroll
        for (int e = 0; e < 4; ++e) {
            const int ix = g + e;
            sT[ix + ix / H] = (&v.x)[e];              // r*21+k
        }
    }
    __syncthreads();

    // own rows r0=2t, r1=2t+1 -> registers
    const int r0 = (2 * t) * RS;
    const int r1 = r0 + RS;
    v2f hv[H];
#pragma unroll
    for (int k = 0; k < H; ++k) { hv[k].x = sT[r0 + k]; hv[k].y = sT[r1 + k]; }
    __syncthreads();   // all hv reads done before overwrite

    // ---- stage cx tile into the same buffer ----
#pragma unroll
    for (int j = 0; j < 10; ++j) {
        const int g = 4 * (t + BLK * j);
        float4 v = *reinterpret_cast<const float4*>(cx + base + g);
#pragma unroll
        for (int e = 0; e < 4; ++e) {
            const int ix = g + e;
            sT[ix + ix / H] = (&v.x)[e];
        }
    }
    __syncthreads();

    v2f cv[H];
#pragma unroll
    for (int k = 0; k < H; ++k) { cv[k].x = sT[r0 + k]; cv[k].y = sT[r1 + k]; }

    // per-row scalars: x is [B,2] -> float4 covers both rows; u -> float2
    const float4 xq = *reinterpret_cast<const float4*>(x + 4 * (size_t)gtid);
    v2f x0; x0.x = xq.x; x0.y = xq.z;
    v2f x1; x1.x = xq.y; x1.y = xq.w;
    const float2 uv2 = *reinterpret_cast<const float2*>(u + 2 * (size_t)gtid);

    // ---- LSTM cell + fused decode, 2 rows packed (v_pk_fma_f32) ----
    v2f l0 = splat2(b_dec[0]), l1 = splat2(b_dec[1]), l2 = splat2(b_dec[2]);
#pragma unroll
    for (int q = 0; q < H; ++q) {
        v2f gi = splat2(b_ih[q]      + b_hh[q])      + x0 * splat2(W_ih[2 * q])          + x1 * splat2(W_ih[2 * q + 1]);
        v2f gf = splat2(b_ih[20 + q] + b_hh[20 + q]) + x0 * splat2(W_ih[2 * (20 + q)])   + x1 * splat2(W_ih[2 * (20 + q) + 1]);
        v2f gg = splat2(b_ih[40 + q] + b_hh[40 + q]) + x0 * splat2(W_ih[2 * (40 + q)])   + x1 * splat2(W_ih[2 * (40 + q) + 1]);
        v2f go = splat2(b_ih[60 + q] + b_hh[60 + q]) + x0 * splat2(W_ih[2 * (60 + q)])   + x1 * splat2(W_ih[2 * (60 + q) + 1]);
#pragma unroll
        for (int k = 0; k < H; ++k) {
            const v2f hk = hv[k];
            gi += hk * splat2(W_hh[(q)      * H + k]);
            gf += hk * splat2(W_hh[(20 + q) * H + k]);
            gg += hk * splat2(W_hh[(40 + q) * H + k]);
            go += hk * splat2(W_hh[(60 + q) * H + k]);
        }
        v2f si, sf, tg, so;
        si.x = sigmoidf_stable(gi.x); si.y = sigmoidf_stable(gi.y);
        sf.x = sigmoidf_stable(gf.x); sf.y = sigmoidf_stable(gf.y);
        tg.x = tanhf(gg.x);           tg.y = tanhf(gg.y);
        so.x = sigmoidf_stable(go.x); so.y = sigmoidf_stable(go.y);
        const v2f cq = sf * cv[q] + si * tg;
        v2f th; th.x = tanhf(cq.x); th.y = tanhf(cq.y);
        const v2f hq = so * th;
        cv[q] = cq;
        sT[r0 + q] = hq.x;   // own rows only; read back in store phase
        sT[r1 + q] = hq.y;
        l0 += hq * splat2(W_dec[q]);
        l1 += hq * splat2(W_dec[20 + q]);
        l2 += hq * splat2(W_dec[40 + q]);
    }

    // ---- softmax + inverse-CDF sample, per row (identical op order) ----
    float a0, s0, a1, s1;
    sample_row(l0.x, l1.x, l2.x, uv2.x, a0, s0);
    sample_row(l0.y, l1.y, l2.y, uv2.y, a1, s1);
    *reinterpret_cast<float2*>(out + 2 * (size_t)gtid) = make_float2(a0, a1);
    *reinterpret_cast<float2*>(out + (size_t)BATCH + 2 * (size_t)gtid) = make_float2(s0, s1);

    __syncthreads();   // all h rows finalized in sT

    float* hout  = out + 2 * (size_t)BATCH;
    float* cout_ = hout + (size_t)H * BATCH;
#pragma unroll
    for (int j = 0; j < 10; ++j) {
        const int g = 4 * (t + BLK * j);
        float4 v;
#pragma unroll
        for (int e = 0; e < 4; ++e) {
            const int ix = g + e;
            (&v.x)[e] = sT[ix + ix / H];
        }
        *reinterpret_cast<float4*>(hout + base + g) = v;
    }
    __syncthreads();   // h-store reads done; safe to overwrite with c

#pragma unroll
    for (int k = 0; k < H; ++k) { sT[r0 + k] = cv[k].x; sT[r1 + k] = cv[k].y; }
    __syncthreads();

#pragma unroll
    for (int j = 0; j < 10; ++j) {
        const int g = 4 * (t + BLK * j);
        float4 v;
#pragma unroll
        for (int e = 0; e < 4; ++e) {
            const int ix = g + e;
            (&v.x)[e] = sT[ix + ix / H];
        }
        *reinterpret_cast<float4*>(cout_ + base + g) = v;
    }
}

extern "C" void kernel_launch(void* const* d_in, const int* in_sizes, int n_in,
                              void* d_out, int out_size, void* d_ws, size_t ws_size,
                              hipStream_t stream) {
    const float* x     = (const float*)d_in[0];
    const float* hx    = (const float*)d_in[1];
    const float* cx    = (const float*)d_in[2];
    const float* u     = (const float*)d_in[3];
    const float* W_ih  = (const float*)d_in[4];
    const float* W_hh  = (const float*)d_in[5];
    const float* b_ih  = (const float*)d_in[6];
    const float* b_hh  = (const float*)d_in[7];
    const float* W_dec = (const float*)d_in[8];
    const float* b_dec = (const float*)d_in[9];
    float* out = (float*)d_out;

    dim3 grid(BATCH / ROWS), block(BLK);
    lstm_coord_kernel<<<grid, block, 0, stream>>>(
        x, hx, cx, u, W_ih, W_hh, b_ih, b_hh, W_dec, b_dec, out);
}

// Round 5
// 147.075 us; speedup vs baseline: 1.5933x; 1.5933x over previous
//
#include <hip/hip_runtime.h>

constexpr int BATCH = 1048576;
constexpr int H = 20;       // hidden
constexpr int BLK = 256;    // threads per block = batch rows per block
constexpr int RS = 21;      // padded LDS row stride (gcd(21,32)=1 -> conflict-free)
constexpr int TILE = BLK * H;   // 5120 floats per tile

// packed-weight layout in d_ws (floats):
//   [0 .. 1599]    Whh_pk: (q*20+k)*4 + {0:Wi,1:Wf,2:Wg,3:Wo}   where Wg_hh[g][q][k]=W_hh[(g*20+q)*20+k]
//   [1600 .. 1759] Wih_pk: q*8 + {Wi0,Wf0,Wg0,Wo0, Wi1,Wf1,Wg1,Wo1}
//   [1760 .. 1839] B_pk:   q*4 + {bi,bf,bg,bo}  (b_ih+b_hh pre-summed, same fp32 add as before)
constexpr int WHH_OFF = 0;
constexpr int WIH_OFF = 1600;
constexpr int B_OFF   = 1760;
constexpr int WS_FLOATS = 1840;

typedef float v2f __attribute__((ext_vector_type(2)));
__device__ __forceinline__ v2f splat2(float s) { v2f r; r.x = s; r.y = s; return r; }

// Branch-free, per-lane bit-identical to the validated if/else version.
__device__ __forceinline__ float sigmoidf_stable(float z) {
    const float e = expf(-fabsf(z));
    const float n = (z >= 0.0f) ? 1.0f : e;
    return n / (1.0f + e);
}

__global__ __launch_bounds__(256) void pack_weights(
    const float* __restrict__ W_ih, const float* __restrict__ W_hh,
    const float* __restrict__ b_ih, const float* __restrict__ b_hh,
    float* __restrict__ ws)
{
    const int i = blockIdx.x * 256 + threadIdx.x;
    if (i < 400) {                      // (q,k) pairs for W_hh
        const int q = i / 20, k = i % 20;
#pragma unroll
        for (int g = 0; g < 4; ++g)
            ws[WHH_OFF + i * 4 + g] = W_hh[(g * 20 + q) * 20 + k];
    }
    if (i < 20) {                       // q rows for W_ih and biases
#pragma unroll
        for (int g = 0; g < 4; ++g) {
            ws[WIH_OFF + i * 8 + g]     = W_ih[(g * 20 + i) * 2 + 0];
            ws[WIH_OFF + i * 8 + 4 + g] = W_ih[(g * 20 + i) * 2 + 1];
            ws[B_OFF   + i * 4 + g]     = b_ih[g * 20 + i] + b_hh[g * 20 + i];
        }
    }
}

__global__ __launch_bounds__(BLK) void lstm_coord_kernel(
    const float* __restrict__ x,
    const float* __restrict__ hx,
    const float* __restrict__ cx,
    const float* __restrict__ u,
    const float* __restrict__ wsp,      // packed weights (uniform -> s_load)
    const float* __restrict__ W_dec,
    const float* __restrict__ b_dec,
    float* __restrict__ out)
{
    __shared__ float sH[BLK * RS];
    __shared__ float sC[BLK * RS];

    const int t = threadIdx.x;

    // ---- coalesced global->LDS staging of hx/cx tiles (verbatim R3) ----
    const size_t base = (size_t)blockIdx.x * TILE;
#pragma unroll
    for (int j = 0; j < 5; ++j) {
        const int g = 4 * (t + BLK * j);
        float4 v = *reinterpret_cast<const float4*>(hx + base + g);
#pragma unroll
        for (int e = 0; e < 4; ++e) {
            const int gg = g + e;
            sH[gg + gg / H] = (&v.x)[e];
        }
        float4 w = *reinterpret_cast<const float4*>(cx + base + g);
#pragma unroll
        for (int e = 0; e < 4; ++e) {
            const int gg = g + e;
            sC[gg + gg / H] = (&w.x)[e];
        }
    }
    __syncthreads();

    const int b = blockIdx.x * BLK + t;

    const float2 xv = *reinterpret_cast<const float2*>(x + 2 * (size_t)b);
    const v2f x0v = splat2(xv.x);
    const v2f x1v = splat2(xv.y);
    const float uv = u[b];

    // own-row hx -> splatted v2f registers ({hk,hk} for packed FMA operand)
    v2f hv2[H];
    const int row = t * RS;
#pragma unroll
    for (int k = 0; k < H; ++k) hv2[k] = splat2(sH[row + k]);

    // ---- LSTM cell + fused decode; matvec packed as {i,f} and {g,o} ----
    // Per-component op order identical to validated R3.
    float l0 = b_dec[0], l1 = b_dec[1], l2 = b_dec[2];
#pragma unroll
    for (int q = 0; q < H; ++q) {
        v2f g01 = *reinterpret_cast<const v2f*>(wsp + B_OFF + 4 * q);       // {bi,bf}
        v2f g23 = *reinterpret_cast<const v2f*>(wsp + B_OFF + 4 * q + 2);   // {bg,bo}
        g01 = g01 + x0v * *reinterpret_cast<const v2f*>(wsp + WIH_OFF + 8 * q);
        g23 = g23 + x0v * *reinterpret_cast<const v2f*>(wsp + WIH_OFF + 8 * q + 2);
        g01 = g01 + x1v * *reinterpret_cast<const v2f*>(wsp + WIH_OFF + 8 * q + 4);
        g23 = g23 + x1v * *reinterpret_cast<const v2f*>(wsp + WIH_OFF + 8 * q + 6);
#pragma unroll
        for (int k = 0; k < H; ++k) {
            const v2f wp01 = *reinterpret_cast<const v2f*>(wsp + WHH_OFF + (q * 20 + k) * 4);
            const v2f wp23 = *reinterpret_cast<const v2f*>(wsp + WHH_OFF + (q * 20 + k) * 4 + 2);
            g01 = g01 + hv2[k] * wp01;
            g23 = g23 + hv2[k] * wp23;
        }
        const float gi = sigmoidf_stable(g01.x);
        const float gf = sigmoidf_stable(g01.y);
        const float gg = tanhf(g23.x);
        const float go = sigmoidf_stable(g23.y);
        const float cq = gf * sC[row + q] + gi * gg;
        const float hq = go * tanhf(cq);
        sC[row + q] = cq;       // own row only
        sH[row + q] = hq;       // own row only
        l0 += hq * W_dec[q];
        l1 += hq * W_dec[20 + q];
        l2 += hq * W_dec[40 + q];
    }

    // ---- log_softmax + inverse-CDF sample (identical op order) ----
    const float m = fmaxf(fmaxf(l0, l1), l2);
    const float s = expf(l0 - m) + expf(l1 - m) + expf(l2 - m);
    const float lse = m + logf(s);
    const float lp0 = l0 - lse, lp1 = l1 - lse, lp2 = l2 - lse;
    const float p0 = expf(lp0), p1 = expf(lp1), p2 = expf(lp2);
    const float c0 = p0;
    const float c1 = c0 + p1;
    const float c2 = c1 + p2;
    int act = (int)(c0 < uv) + (int)(c1 < uv) + (int)(c2 < uv);
    act = act > 2 ? 2 : act;
    const float slp = (act == 0) ? lp0 : ((act == 1) ? lp1 : lp2);

    out[b] = (float)act;
    out[(size_t)BATCH + b] = slp;

    __syncthreads();

    // ---- coalesced LDS->global stores of h/c tiles (verbatim R3) ----
    float* hout  = out + 2 * (size_t)BATCH;
    float* cout_ = hout + (size_t)H * BATCH;
#pragma unroll
    for (int j = 0; j < 5; ++j) {
        const int g = 4 * (t + BLK * j);
        float4 v, w;
#pragma unroll
        for (int e = 0; e < 4; ++e) {
            const int gg = g + e;
            (&v.x)[e] = sH[gg + gg / H];
            (&w.x)[e] = sC[gg + gg / H];
        }
        *reinterpret_cast<float4*>(hout  + base + g) = v;
        *reinterpret_cast<float4*>(cout_ + base + g) = w;
    }
}

extern "C" void kernel_launch(void* const* d_in, const int* in_sizes, int n_in,
                              void* d_out, int out_size, void* d_ws, size_t ws_size,
                              hipStream_t stream) {
    const float* x     = (const float*)d_in[0];
    const float* hx    = (const float*)d_in[1];
    const float* cx    = (const float*)d_in[2];
    const float* u     = (const float*)d_in[3];
    const float* W_ih  = (const float*)d_in[4];
    const float* W_hh  = (const float*)d_in[5];
    const float* b_ih  = (const float*)d_in[6];
    const float* b_hh  = (const float*)d_in[7];
    const float* W_dec = (const float*)d_in[8];
    const float* b_dec = (const float*)d_in[9];
    float* out = (float*)d_out;
    float* ws  = (float*)d_ws;

    pack_weights<<<2, 256, 0, stream>>>(W_ih, W_hh, b_ih, b_hh, ws);

    dim3 grid(BATCH / BLK), block(BLK);
    lstm_coord_kernel<<<grid, block, 0, stream>>>(
        x, hx, cx, u, ws, W_dec, b_dec, out);
}

// Round 6
// 126.550 us; speedup vs baseline: 1.8517x; 1.1622x over previous
//
#include <hip/hip_runtime.h>

constexpr int BATCH = 1048576;
constexpr int H = 20;       // hidden
constexpr int BLK = 256;    // threads per block = batch rows per block
constexpr int RS = 21;      // padded LDS row stride (gcd(21,32)=1 -> conflict-free)
constexpr int TILE = BLK * H;   // 5120 floats per tile

// packed-weight layout in d_ws (floats) — identical to validated R5:
constexpr int WHH_OFF = 0;
constexpr int WIH_OFF = 1600;
constexpr int B_OFF   = 1760;

typedef float v2f __attribute__((ext_vector_type(2)));
__device__ __forceinline__ v2f splat2(float s) { v2f r; r.x = s; r.y = s; return r; }

// ---- exact path (bit-compatible with validated R3/R5 kernels) ----
__device__ __forceinline__ float sigmoidf_stable(float z) {
    const float e = expf(-fabsf(z));
    const float n = (z >= 0.0f) ? 1.0f : e;
    return n / (1.0f + e);
}

// ---- fast path: native exp / rcp, abs error on cdf bounded ~3e-5 ----
__device__ __forceinline__ float fsigmoid(float z) {
    const float e = __expf(-z);                  // v_mul + v_exp
    return __builtin_amdgcn_rcpf(1.0f + e);      // v_add + v_rcp
}
__device__ __forceinline__ float ftanh(float z) {
    const float e = __expf(2.0f * z);
    return 1.0f - 2.0f * __builtin_amdgcn_rcpf(e + 1.0f);
}

constexpr float EPS_GUARD = 1e-4f;   // >=3x the fast-path cdf error bound

__global__ __launch_bounds__(256) void pack_weights(
    const float* __restrict__ W_ih, const float* __restrict__ W_hh,
    const float* __restrict__ b_ih, const float* __restrict__ b_hh,
    float* __restrict__ ws)
{
    const int i = blockIdx.x * 256 + threadIdx.x;
    if (i < 400) {
        const int q = i / 20, k = i % 20;
#pragma unroll
        for (int g = 0; g < 4; ++g)
            ws[WHH_OFF + i * 4 + g] = W_hh[(g * 20 + q) * 20 + k];
    }
    if (i < 20) {
#pragma unroll
        for (int g = 0; g < 4; ++g) {
            ws[WIH_OFF + i * 8 + g]     = W_ih[(g * 20 + i) * 2 + 0];
            ws[WIH_OFF + i * 8 + 4 + g] = W_ih[(g * 20 + i) * 2 + 1];
            ws[B_OFF   + i * 4 + g]     = b_ih[g * 20 + i] + b_hh[g * 20 + i];
        }
    }
}

__global__ __launch_bounds__(BLK) void lstm_coord_kernel(
    const float* __restrict__ x,
    const float* __restrict__ hx,
    const float* __restrict__ cx,
    const float* __restrict__ u,
    const float* __restrict__ wsp,
    const float* __restrict__ W_dec,
    const float* __restrict__ b_dec,
    float* __restrict__ out)
{
    __shared__ float sH[BLK * RS];
    __shared__ float sC[BLK * RS];

    const int t = threadIdx.x;

    // ---- coalesced global->LDS staging of hx/cx tiles (verbatim R5) ----
    const size_t base = (size_t)blockIdx.x * TILE;
#pragma unroll
    for (int j = 0; j < 5; ++j) {
        const int g = 4 * (t + BLK * j);
        float4 v = *reinterpret_cast<const float4*>(hx + base + g);
#pragma unroll
        for (int e = 0; e < 4; ++e) {
            const int gg = g + e;
            sH[gg + gg / H] = (&v.x)[e];
        }
        float4 w = *reinterpret_cast<const float4*>(cx + base + g);
#pragma unroll
        for (int e = 0; e < 4; ++e) {
            const int gg = g + e;
            sC[gg + gg / H] = (&w.x)[e];
        }
    }
    __syncthreads();

    const int b = blockIdx.x * BLK + t;

    const float2 xv = *reinterpret_cast<const float2*>(x + 2 * (size_t)b);
    const v2f x0v = splat2(xv.x);
    const v2f x1v = splat2(xv.y);
    const float uv = u[b];

    v2f hv2[H];                      // stays live for the exact fallback
    const int row = t * RS;
#pragma unroll
    for (int k = 0; k < H; ++k) hv2[k] = splat2(sH[row + k]);

    // ---- FAST path: LSTM cell + fused decode (matvec bit-identical to R5) ----
    float l0 = b_dec[0], l1 = b_dec[1], l2 = b_dec[2];
#pragma unroll
    for (int q = 0; q < H; ++q) {
        v2f g01 = *reinterpret_cast<const v2f*>(wsp + B_OFF + 4 * q);
        v2f g23 = *reinterpret_cast<const v2f*>(wsp + B_OFF + 4 * q + 2);
        g01 = g01 + x0v * *reinterpret_cast<const v2f*>(wsp + WIH_OFF + 8 * q);
        g23 = g23 + x0v * *reinterpret_cast<const v2f*>(wsp + WIH_OFF + 8 * q + 2);
        g01 = g01 + x1v * *reinterpret_cast<const v2f*>(wsp + WIH_OFF + 8 * q + 4);
        g23 = g23 + x1v * *reinterpret_cast<const v2f*>(wsp + WIH_OFF + 8 * q + 6);
#pragma unroll
        for (int k = 0; k < H; ++k) {
            const v2f wp01 = *reinterpret_cast<const v2f*>(wsp + WHH_OFF + (q * 20 + k) * 4);
            const v2f wp23 = *reinterpret_cast<const v2f*>(wsp + WHH_OFF + (q * 20 + k) * 4 + 2);
            g01 = g01 + hv2[k] * wp01;
            g23 = g23 + hv2[k] * wp23;
        }
        const float gi = fsigmoid(g01.x);
        const float gf = fsigmoid(g01.y);
        const float gg = ftanh(g23.x);
        const float go = fsigmoid(g23.y);
        const float cq = gf * sC[row + q] + gi * gg;
        const float hq = go * ftanh(cq);
        sC[row + q] = cq;       // own row only
        sH[row + q] = hq;       // own row only
        l0 += hq * W_dec[q];
        l1 += hq * W_dec[20 + q];
        l2 += hq * W_dec[40 + q];
    }

    // ---- fast softmax + inverse-CDF sample ----
    const float m = fmaxf(fmaxf(l0, l1), l2);
    const float s = __expf(l0 - m) + __expf(l1 - m) + __expf(l2 - m);
    const float lse = m + __logf(s);
    const float lp0 = l0 - lse, lp1 = l1 - lse, lp2 = l2 - lse;
    const float p0 = __expf(lp0), p1 = __expf(lp1), p2 = __expf(lp2);
    const float c0 = p0;
    const float c1 = c0 + p1;
    const float c2 = c1 + p2;
    int acti = (int)(c0 < uv) + (int)(c1 < uv) + (int)(c2 < uv);
    acti = acti > 2 ? 2 : acti;
    float act = (float)acti;
    float slp = (acti == 0) ? lp0 : ((acti == 1) ? lp1 : lp2);

    // ---- guard: if u is within EPS of any fast cdf boundary, redo exactly ----
    const float d0 = fabsf(c0 - uv), d1 = fabsf(c1 - uv), d2 = fabsf(c2 - uv);
    const bool risky = fminf(fminf(d0, d1), d2) < EPS_GUARD;
    if (risky) {
        const float* cxr = cx + (size_t)b * H;   // original cx (sC was overwritten)
        float l0e = b_dec[0], l1e = b_dec[1], l2e = b_dec[2];
#pragma unroll 1
        for (int q = 0; q < H; ++q) {
            v2f g01 = *reinterpret_cast<const v2f*>(wsp + B_OFF + 4 * q);
            v2f g23 = *reinterpret_cast<const v2f*>(wsp + B_OFF + 4 * q + 2);
            g01 = g01 + x0v * *reinterpret_cast<const v2f*>(wsp + WIH_OFF + 8 * q);
            g23 = g23 + x0v * *reinterpret_cast<const v2f*>(wsp + WIH_OFF + 8 * q + 2);
            g01 = g01 + x1v * *reinterpret_cast<const v2f*>(wsp + WIH_OFF + 8 * q + 4);
            g23 = g23 + x1v * *reinterpret_cast<const v2f*>(wsp + WIH_OFF + 8 * q + 6);
#pragma unroll
            for (int k = 0; k < H; ++k) {
                const v2f wp01 = *reinterpret_cast<const v2f*>(wsp + WHH_OFF + (q * 20 + k) * 4);
                const v2f wp23 = *reinterpret_cast<const v2f*>(wsp + WHH_OFF + (q * 20 + k) * 4 + 2);
                g01 = g01 + hv2[k] * wp01;
                g23 = g23 + hv2[k] * wp23;
            }
            const float gi = sigmoidf_stable(g01.x);
            const float gf = sigmoidf_stable(g01.y);
            const float gg = tanhf(g23.x);
            const float go = sigmoidf_stable(g23.y);
            const float cq = gf * cxr[q] + gi * gg;
            const float hq = go * tanhf(cq);
            l0e += hq * W_dec[q];
            l1e += hq * W_dec[20 + q];
            l2e += hq * W_dec[40 + q];
        }
        const float me = fmaxf(fmaxf(l0e, l1e), l2e);
        const float se = expf(l0e - me) + expf(l1e - me) + expf(l2e - me);
        const float lsee = me + logf(se);
        const float lp0e = l0e - lsee, lp1e = l1e - lsee, lp2e = l2e - lsee;
        const float p0e = expf(lp0e), p1e = expf(lp1e), p2e = expf(lp2e);
        const float c0e = p0e;
        const float c1e = c0e + p1e;
        const float c2e = c1e + p2e;
        int ae = (int)(c0e < uv) + (int)(c1e < uv) + (int)(c2e < uv);
        ae = ae > 2 ? 2 : ae;
        act = (float)ae;
        slp = (ae == 0) ? lp0e : ((ae == 1) ? lp1e : lp2e);
    }

    out[b] = act;
    out[(size_t)BATCH + b] = slp;

    __syncthreads();

    // ---- coalesced LDS->global stores of h/c tiles (verbatim R5) ----
    float* hout  = out + 2 * (size_t)BATCH;
    float* cout_ = hout + (size_t)H * BATCH;
#pragma unroll
    for (int j = 0; j < 5; ++j) {
        const int g = 4 * (t + BLK * j);
        float4 v, w;
#pragma unroll
        for (int e = 0; e < 4; ++e) {
            const int gg = g + e;
            (&v.x)[e] = sH[gg + gg / H];
            (&w.x)[e] = sC[gg + gg / H];
        }
        *reinterpret_cast<float4*>(hout  + base + g) = v;
        *reinterpret_cast<float4*>(cout_ + base + g) = w;
    }
}

extern "C" void kernel_launch(void* const* d_in, const int* in_sizes, int n_in,
                              void* d_out, int out_size, void* d_ws, size_t ws_size,
                              hipStream_t stream) {
    const float* x     = (const float*)d_in[0];
    const float* hx    = (const float*)d_in[1];
    const float* cx    = (const float*)d_in[2];
    const float* u     = (const float*)d_in[3];
    const float* W_ih  = (const float*)d_in[4];
    const float* W_hh  = (const float*)d_in[5];
    const float* b_ih  = (const float*)d_in[6];
    const float* b_hh  = (const float*)d_in[7];
    const float* W_dec = (const float*)d_in[8];
    const float* b_dec = (const float*)d_in[9];
    float* out = (float*)d_out;
    float* ws  = (float*)d_ws;

    pack_weights<<<2, 256, 0, stream>>>(W_ih, W_hh, b_ih, b_hh, ws);

    dim3 grid(BATCH / BLK), block(BLK);
    lstm_coord_kernel<<<grid, block, 0, stream>>>(
        x, hx, cx, u, ws, W_dec, b_dec, out);
}